// Round 3
// baseline (480.540 us; speedup 1.0000x reference)
//
#include <hip/hip_runtime.h>

// ContinuousPool: 10x [cur += p*(maxpool3x3_same(cur)-cur)] then avgpool2x2.
// One block (256 thr) per (n,c) plane; thread tile = 8 rows x 8 cols.
// - Horizontal 3-max halo via DPP row_shr/row_shl (tx == 16-lane DPP row-lane;
//   out-of-row lanes receive old = -inf == reduce_window's -inf padding).
// - Vertical halo: only hmax of tile boundary rows through LDS. Per-thread
//   LDS cost is constant in tile height, so the 8-row tile halves LDS-pipe
//   traffic vs a 4-row tile (the R2 kernel).
// - Double-buffered halo LDS -> ONE barrier per timestep; 31.7 KB LDS +
//   launch_bounds(256,4) -> 4 blocks/CU (4 independent barrier groups).
// - Latency order: after the barrier both halo reads issue; row 0 (top halo)
//   is consumed after ~20 VALU, row 7 (bottom halo) after the whole interior
//   roll (~150 VALU) -> ds_read latency fully covered.

#define TSTEPS 10
#define PW 128
#define HP 132   // LDS row pitch (floats): 528B = 16 mod 128 -> bank stagger per ty

__device__ __forceinline__ float dpp_left(float x) {
    // row_shr:1 -> lane i gets lane i-1 within its 16-lane DPP row; row-lane 0 -> old(-inf)
    int r = __builtin_amdgcn_update_dpp((int)0xff800000, __float_as_int(x),
                                        0x111, 0xf, 0xf, false);
    return __int_as_float(r);
}
__device__ __forceinline__ float dpp_right(float x) {
    // row_shl:1 -> lane i gets lane i+1; row-lane 15 -> old(-inf)
    int r = __builtin_amdgcn_update_dpp((int)0xff800000, __float_as_int(x),
                                        0x101, 0xf, 0xf, false);
    return __int_as_float(r);
}

__device__ __forceinline__ float max3f(float a, float b, float c) {
    return fmaxf(fmaxf(a, b), c);   // folds to v_max3_f32
}

// h[c] = max(v[c-1], v[c], v[c+1]) over the thread's 8-wide row, halo via DPP.
__device__ __forceinline__ void hmax_row(const float* v, float* h) {
    float vl = dpp_left(v[7]);   // left neighbor thread's rightmost col
    float vr = dpp_right(v[0]);  // right neighbor thread's leftmost col
    h[0] = max3f(vl, v[0], v[1]);
#pragma unroll
    for (int c = 1; c < 7; ++c) h[c] = max3f(v[c - 1], v[c], v[c + 1]);
    h[7] = max3f(v[6], v[7], vr);
}

__device__ __forceinline__ void ld8(const float* a, float* d) {
    float4 u = ((const float4*)a)[0], v = ((const float4*)a)[1];
    d[0] = u.x; d[1] = u.y; d[2] = u.z; d[3] = u.w;
    d[4] = v.x; d[5] = v.y; d[6] = v.z; d[7] = v.w;
}
__device__ __forceinline__ void st8(float* a, const float* d) {
    ((float4*)a)[0] = make_float4(d[0], d[1], d[2], d[3]);
    ((float4*)a)[1] = make_float4(d[4], d[5], d[6], d[7]);
}

// One timestep. topBuf[i] = hTop of tile (i+1); botBuf[i] = hBot of tile i.
__device__ __forceinline__ void do_step(float cur[8][8], float p, int tx, int ty,
                                        float* __restrict__ topBuf,
                                        float* __restrict__ botBuf) {
    const float NEG = -__builtin_huge_valf();
    const int x0 = tx * 8;

    // ---- pre-barrier: hmax of tile boundary rows -> LDS ----
    float hTop[8], hBot[8];
    hmax_row(cur[0], hTop);
    hmax_row(cur[7], hBot);
    if (ty > 0)  st8(topBuf + (ty - 1) * HP + x0, hTop);
    if (ty < 15) st8(botBuf + ty * HP + x0, hBot);

    __syncthreads();

    // ---- issue both halo reads immediately ----
    float hmE[8], hnE[8];
    if (ty > 0) {
        ld8(botBuf + (ty - 1) * HP + x0, hmE);   // hBot of tile above = h(-1)
    } else {
#pragma unroll
        for (int c = 0; c < 8; ++c) hmE[c] = NEG;
    }
    if (ty < 15) {
        ld8(topBuf + ty * HP + x0, hnE);         // hTop of tile below = h(8)
    } else {
#pragma unroll
        for (int c = 0; c < 8; ++c) hnE[c] = NEG;
    }

    // ---- row 0 update (consumes hmE early; hTop/hmE die here) ----
    float A[8], B[8];
    hmax_row(cur[1], B);                          // h1 (pre-update cur[1])
#pragma unroll
    for (int c = 0; c < 8; ++c) {
        float v = max3f(hmE[c], hTop[c], B[c]);
        cur[0][c] = fmaf(p, v - cur[0][c], cur[0][c]);
        A[c] = hTop[c];                           // roll start: A=h0, B=h1
    }

    // ---- interior rows 1..6, rolling 3-row window (all local) ----
#pragma unroll
    for (int r = 1; r < 7; ++r) {
        float C[8];
        if (r < 6) {
            hmax_row(cur[r + 1], C);              // h(r+1), pre-update
        } else {
#pragma unroll
            for (int c = 0; c < 8; ++c) C[c] = hBot[c];   // h7
        }
#pragma unroll
        for (int c = 0; c < 8; ++c) {
            float v = max3f(A[c], B[c], C[c]);
            cur[r][c] = fmaf(p, v - cur[r][c], cur[r][c]);
            A[c] = B[c]; B[c] = C[c];
        }
    }

    // ---- row 7 (consumes hnE after ~150 VALU of cover): h6,h7,hnE ----
#pragma unroll
    for (int c = 0; c < 8; ++c) {
        float v = max3f(A[c], B[c], hnE[c]);
        cur[7][c] = fmaf(p, v - cur[7][c], cur[7][c]);
    }
    // no trailing barrier: next step writes the OTHER buffer; this buffer is
    // rewritten only after the NEXT step's barrier, by which time all waves
    // have finished this step's reads (reads precede that barrier per-wave).
}

__global__ __launch_bounds__(256, 4)
void cpool_kernel(const float* __restrict__ x, const float* __restrict__ ps,
                  float* __restrict__ out) {
    __shared__ float lds[2][2][15 * HP];   // [buf][top=0/bot=1] : 31,680 B

    const int b = blockIdx.x;              // plane id = n*96 + c
    const float p = ps[b % 96];

    const int tx = threadIdx.x & 15;       // DPP row-lane
    const int ty = threadIdx.x >> 4;       // 0..15, 8 rows each
    const int x0 = tx * 8;
    const int y0 = ty * 8;

    const float* __restrict__ xp = x + (size_t)b * (PW * PW);

    float cur[8][8];
#pragma unroll
    for (int r = 0; r < 8; ++r) ld8(xp + (y0 + r) * PW + x0, cur[r]);

#pragma unroll 1
    for (int tt = 0; tt < TSTEPS / 2; ++tt) {
        do_step(cur, p, tx, ty, lds[0][0], lds[0][1]);
        do_step(cur, p, tx, ty, lds[1][0], lds[1][1]);
    }

    // ---- epilogue: 2x2 avg pool -> 4 rows x 4 cols per thread ----
    float* __restrict__ op = out + (size_t)b * (64 * 64);
#pragma unroll
    for (int r2 = 0; r2 < 4; ++r2) {
        float4 o;
        o.x = 0.25f * (cur[2*r2][0] + cur[2*r2][1] + cur[2*r2+1][0] + cur[2*r2+1][1]);
        o.y = 0.25f * (cur[2*r2][2] + cur[2*r2][3] + cur[2*r2+1][2] + cur[2*r2+1][3]);
        o.z = 0.25f * (cur[2*r2][4] + cur[2*r2][5] + cur[2*r2+1][4] + cur[2*r2+1][5]);
        o.w = 0.25f * (cur[2*r2][6] + cur[2*r2][7] + cur[2*r2+1][6] + cur[2*r2+1][7]);
        *(float4*)(op + (size_t)((ty * 4 + r2) * 64 + tx * 4)) = o;
    }
}

extern "C" void kernel_launch(void* const* d_in, const int* in_sizes, int n_in,
                              void* d_out, int out_size, void* d_ws, size_t ws_size,
                              hipStream_t stream) {
    const float* x  = (const float*)d_in[0];   // (32,96,128,128) fp32
    const float* ps = (const float*)d_in[1];   // (1,96,1,1) fp32
    float* out = (float*)d_out;                // (32,96,64,64) fp32
    (void)in_sizes; (void)n_in; (void)out_size; (void)d_ws; (void)ws_size;

    cpool_kernel<<<dim3(32 * 96), dim3(256), 0, stream>>>(x, ps, out);
}

// Round 4
// 310.579 us; speedup vs baseline: 1.5472x; 1.5472x over previous
//
#include <hip/hip_runtime.h>

// ContinuousPool: 10x [cur += p*(maxpool3x3_same(cur)-cur)] then avgpool2x2.
// ZERO-SYNC temporal-blocked design: one block (256 thr = 4 waves) per (n,c)
// plane; each WAVE independently owns a 32-row band and loads it plus a
// 10-row halo each side (trapezoid). All 10 timesteps run with NO barriers
// and NO LDS: halo rows go stale 1 row/step, owned rows stay exact.
//  - lane L holds cols {2L, 2L+1} (full 128-col width per wave).
//  - horizontal 3-max halo via DPP wave_shr:1 / wave_shl:1 (full-wave lane
//    shift; invalid end lanes get old = -inf == reduce_window padding).
//  - plane-edge waves load fewer rows (42) and get exact -inf padding.
// R3 lesson: launch_bounds(256,4) (cap 128 VGPR) made the allocator spill
// ~850MB to scratch. Here: (256,3) -> cap ~170 VGPR vs ~125 needed.

#define PW 128
#define TSTEPS 10

__device__ __forceinline__ float dpp_wave_left(float x) {
    // wave_shr:1 -> lane i gets lane i-1 across all 64 lanes; lane 0 -> old(-inf)
    int r = __builtin_amdgcn_update_dpp((int)0xff800000, __float_as_int(x),
                                        0x138, 0xf, 0xf, false);
    return __int_as_float(r);
}
__device__ __forceinline__ float dpp_wave_right(float x) {
    // wave_shl:1 -> lane i gets lane i+1 across all 64 lanes; lane 63 -> old(-inf)
    int r = __builtin_amdgcn_update_dpp((int)0xff800000, __float_as_int(x),
                                        0x130, 0xf, 0xf, false);
    return __int_as_float(r);
}

__device__ __forceinline__ float max3f(float a, float b, float c) {
    return fmaxf(fmaxf(a, b), c);   // v_max3_f32
}

// One wave, one row-band: NROWS loaded rows starting at plane row row_base.
// Owned (exact) rows are rs in [RS0, RS0+32). Lane L covers cols 2L, 2L+1.
template<int NROWS, int RS0>
__device__ __forceinline__ void run_band(const float* __restrict__ xp,
                                         float* __restrict__ op,
                                         float p, int lane, int row_base,
                                         int out_row0)
{
    float c0[NROWS], c1[NROWS];
    const float* src = xp + (size_t)row_base * PW + 2 * lane;
#pragma unroll
    for (int rs = 0; rs < NROWS; ++rs) {
        float2 v = *(const float2*)(src + rs * PW);
        c0[rs] = v.x; c1[rs] = v.y;
    }

    const float NEG = -__builtin_huge_valf();

#pragma unroll 1
    for (int t = 0; t < TSTEPS; ++t) {
        // rolling 3-row window of horizontal maxes: hp (row rs-1), hc (rs), hn (rs+1)
        float hp0 = NEG, hp1 = NEG;
        float hc0, hc1;
        {
            float l = dpp_wave_left(c1[0]);     // col 2L-1
            float r = dpp_wave_right(c0[0]);    // col 2L+2
            hc0 = max3f(l, c0[0], c1[0]);
            hc1 = max3f(c0[0], c1[0], r);
        }
#pragma unroll
        for (int rs = 0; rs < NROWS; ++rs) {
            float hn0, hn1;
            if (rs < NROWS - 1) {
                float l = dpp_wave_left(c1[rs + 1]);   // pre-update values
                float r = dpp_wave_right(c0[rs + 1]);
                hn0 = max3f(l, c0[rs + 1], c1[rs + 1]);
                hn1 = max3f(c0[rs + 1], c1[rs + 1], r);
            } else {
                hn0 = NEG; hn1 = NEG;   // beyond loaded range (edge: exact pad;
            }                           // interior: row already stale -> harmless)
            float v0 = max3f(hp0, hc0, hn0);
            float v1 = max3f(hp1, hc1, hn1);
            c0[rs] = fmaf(p, v0 - c0[rs], c0[rs]);
            c1[rs] = fmaf(p, v1 - c1[rs], c1[rs]);
            hp0 = hc0; hp1 = hc1; hc0 = hn0; hc1 = hn1;
        }
    }

    // 2x2 avg pool over owned rows; out col L = cols {2L,2L+1} -> coalesced.
#pragma unroll
    for (int j = 0; j < 16; ++j) {
        const int rs = RS0 + 2 * j;
        float o = 0.25f * (c0[rs] + c1[rs] + c0[rs + 1] + c1[rs + 1]);
        op[(size_t)(out_row0 + j) * 64 + lane] = o;
    }
}

__global__ __launch_bounds__(256, 3)
void cpool_kernel(const float* __restrict__ x, const float* __restrict__ ps,
                  float* __restrict__ out)
{
    const int b = blockIdx.x;              // plane id = n*96 + c
    const float p = ps[b % 96];
    const int lane = threadIdx.x & 63;
    const int w = threadIdx.x >> 6;        // wave id 0..3 (uniform per wave)

    const float* xp = x + (size_t)b * (PW * PW);
    float* op = out + (size_t)b * (64 * 64);

    if (w == 0) {
        run_band<42, 0>(xp, op, p, lane, 0, 0);          // rows [0,42), own [0,32)
    } else if (w == 3) {
        run_band<42, 10>(xp, op, p, lane, 86, 48);       // rows [86,128), own [96,128)
    } else {
        run_band<52, 10>(xp, op, p, lane, 32 * w - 10,   // rows [32w-10,32w+42),
                         16 * w);                        // own [32w,32w+32)
    }
}

extern "C" void kernel_launch(void* const* d_in, const int* in_sizes, int n_in,
                              void* d_out, int out_size, void* d_ws, size_t ws_size,
                              hipStream_t stream) {
    const float* x  = (const float*)d_in[0];   // (32,96,128,128) fp32
    const float* ps = (const float*)d_in[1];   // (1,96,1,1) fp32
    float* out = (float*)d_out;                // (32,96,64,64) fp32
    (void)in_sizes; (void)n_in; (void)out_size; (void)d_ws; (void)ws_size;

    cpool_kernel<<<dim3(32 * 96), dim3(256), 0, stream>>>(x, ps, out);
}

// Round 5
// 309.774 us; speedup vs baseline: 1.5513x; 1.0026x over previous
//
#include <hip/hip_runtime.h>

// ContinuousPool: 10x [cur += p*(maxpool3x3_same(cur)-cur)] then avgpool2x2.
// ZERO-SYNC temporal-blocked (trapezoid) design, as R4: one block (4 waves)
// per (n,c) plane; each wave owns a 32-row band + 10-row stale halo per side,
// runs all 10 steps with no barriers / no LDS. Lane L holds cols {2L,2L+1};
// horizontal halo via DPP wave_shr:1/wave_shl:1 (old = -inf == padding).
//
// R4 LESSON (the big one): float c0[52] arrays were NEVER promoted to
// registers (VGPR_Count=60 < 104 state floats) -> scratch round-trips doubled
// the instruction stream. Fix: band state lives in ext_vector_type(52)
// vectors (first-class SSA, no alloca), and all row-indexed loops are
// template-recursive so every vector subscript is a compile-time constant.

#define PW 128
#define TSTEPS 10

typedef float float52 __attribute__((ext_vector_type(52)));

__device__ __forceinline__ float dpp_wave_left(float x) {
    // wave_shr:1 -> lane i gets lane i-1 across all 64 lanes; lane 0 -> old(-inf)
    int r = __builtin_amdgcn_update_dpp((int)0xff800000, __float_as_int(x),
                                        0x138, 0xf, 0xf, false);
    return __int_as_float(r);
}
__device__ __forceinline__ float dpp_wave_right(float x) {
    // wave_shl:1 -> lane i gets lane i+1 across all 64 lanes; lane 63 -> old(-inf)
    int r = __builtin_amdgcn_update_dpp((int)0xff800000, __float_as_int(x),
                                        0x130, 0xf, 0xf, false);
    return __int_as_float(r);
}

__device__ __forceinline__ float max3f(float a, float b, float c) {
    return fmaxf(fmaxf(a, b), c);   // v_max3_f32
}

// ---- load rows [0,NROWS) of the band: constant-index insert into vectors ----
template<int RS, int NROWS>
__device__ __forceinline__ void load_rows(const float* __restrict__ src,
                                          float52& c0, float52& c1) {
    float2 v = *(const float2*)(src + RS * PW);
    c0[RS] = v.x; c1[RS] = v.y;
    if constexpr (RS + 1 < NROWS) load_rows<RS + 1, NROWS>(src, c0, c1);
}

// ---- one timestep, rolling 3-row window of horizontal maxes ----
// hp = h(row RS-1), hc = h(row RS); computes hn = h(row RS+1) then updates row RS.
template<int RS, int NROWS>
__device__ __forceinline__ void row_steps(float52& c0, float52& c1, float p,
                                          float hp0, float hp1,
                                          float hc0, float hc1) {
    const float NEG = -__builtin_huge_valf();
    float hn0, hn1;
    if constexpr (RS < NROWS - 1) {
        float l = dpp_wave_left(c1[RS + 1]);    // col 2L-1 (pre-update value)
        float r = dpp_wave_right(c0[RS + 1]);   // col 2L+2
        hn0 = max3f(l, c0[RS + 1], c1[RS + 1]);
        hn1 = max3f(c0[RS + 1], c1[RS + 1], r);
    } else {
        hn0 = NEG; hn1 = NEG;   // beyond band (edge: exact pad; interior: stale row)
    }
    float v0 = max3f(hp0, hc0, hn0);
    float v1 = max3f(hp1, hc1, hn1);
    c0[RS] = fmaf(p, v0 - c0[RS], c0[RS]);
    c1[RS] = fmaf(p, v1 - c1[RS], c1[RS]);
    if constexpr (RS + 1 < NROWS)
        row_steps<RS + 1, NROWS>(c0, c1, p, hc0, hc1, hn0, hn1);
}

// ---- epilogue: 2x2 avg pool over the 32 owned rows ----
template<int J, int RS0>
__device__ __forceinline__ void pool_rows(const float52& c0, const float52& c1,
                                          float* __restrict__ op,
                                          int out_row0, int lane) {
    constexpr int rs = RS0 + 2 * J;
    float o = 0.25f * (c0[rs] + c1[rs] + c0[rs + 1] + c1[rs + 1]);
    op[(size_t)(out_row0 + J) * 64 + lane] = o;
    if constexpr (J + 1 < 16) pool_rows<J + 1, RS0>(c0, c1, op, out_row0, lane);
}

// One wave, one row-band: NROWS loaded rows from plane row row_base; owned
// (exact) rows are [RS0, RS0+32). Lane L covers cols 2L, 2L+1.
template<int NROWS, int RS0>
__device__ __forceinline__ void run_band(const float* __restrict__ xp,
                                         float* __restrict__ op,
                                         float p, int lane, int row_base,
                                         int out_row0)
{
    const float NEG = -__builtin_huge_valf();
    float52 c0, c1;
    load_rows<0, NROWS>(xp + (size_t)row_base * PW + 2 * lane, c0, c1);

#pragma unroll 1
    for (int t = 0; t < TSTEPS; ++t) {
        float l = dpp_wave_left(c1[0]);
        float r = dpp_wave_right(c0[0]);
        float hc0 = max3f(l, c0[0], c1[0]);
        float hc1 = max3f(c0[0], c1[0], r);
        row_steps<0, NROWS>(c0, c1, p, NEG, NEG, hc0, hc1);
    }

    pool_rows<0, RS0>(c0, c1, op, out_row0, lane);
}

__global__ __launch_bounds__(256, 3)
void cpool_kernel(const float* __restrict__ x, const float* __restrict__ ps,
                  float* __restrict__ out)
{
    const int b = blockIdx.x;              // plane id = n*96 + c
    const float p = ps[b % 96];
    const int lane = threadIdx.x & 63;
    const int w = threadIdx.x >> 6;        // wave id 0..3 (wave-uniform)

    const float* xp = x + (size_t)b * (PW * PW);
    float* op = out + (size_t)b * (64 * 64);

    if (w == 0) {
        run_band<42, 0>(xp, op, p, lane, 0, 0);          // rows [0,42), own [0,32)
    } else if (w == 3) {
        run_band<42, 10>(xp, op, p, lane, 86, 48);       // rows [86,128), own [96,128)
    } else {
        run_band<52, 10>(xp, op, p, lane, 32 * w - 10,   // rows [32w-10,32w+42)
                         16 * w);                        // own [32w,32w+32)
    }
}

extern "C" void kernel_launch(void* const* d_in, const int* in_sizes, int n_in,
                              void* d_out, int out_size, void* d_ws, size_t ws_size,
                              hipStream_t stream) {
    const float* x  = (const float*)d_in[0];   // (32,96,128,128) fp32
    const float* ps = (const float*)d_in[1];   // (1,96,1,1) fp32
    float* out = (float*)d_out;                // (32,96,64,64) fp32
    (void)in_sizes; (void)n_in; (void)out_size; (void)d_ws; (void)ws_size;

    cpool_kernel<<<dim3(32 * 96), dim3(256), 0, stream>>>(x, ps, out);
}